// Round 22
// baseline (2664.385 us; speedup 1.0000x reference)
//
#include <hip/hip_runtime.h>
#include <hip/hip_bf16.h>

typedef float  f32x4  __attribute__((ext_vector_type(4)));
typedef short  short8 __attribute__((ext_vector_type(8)));
typedef short  bf4    __attribute__((ext_vector_type(4)));

#define MFMA16(a,b,c) __builtin_amdgcn_mfma_f32_16x16x32_bf16((a),(b),(c),0,0,0)
#define GLOADLDS(SRC, DST) __builtin_amdgcn_global_load_lds( \
  (const __attribute__((address_space(1))) void*)(SRC), \
  (__attribute__((address_space(3))) void*)(DST), 16, 0, 0)

__device__ __forceinline__ short tobf(float f){
  unsigned u = __float_as_uint(f);
  u += 0x7fffu + ((u >> 16) & 1u);
  return (short)(u >> 16);
}
__device__ __forceinline__ float frombf(short s){
  return __uint_as_float(((unsigned)(unsigned short)s) << 16);
}
__device__ __forceinline__ float sigf(float x){
  return 1.f / (1.f + __expf(-x));
}
__device__ __forceinline__ float tanhf_(float x){
  float ax = fabsf(x);
  float e  = __expf(-2.f * ax);
  float t  = (1.f - e) / (1.f + e);
  return x >= 0.f ? t : -t;
}
__device__ __forceinline__ bf4 pack4(f32x4 v){
  bf4 r; r[0]=tobf(v[0]); r[1]=tobf(v[1]); r[2]=tobf(v[2]); r[3]=tobf(v[3]); return r;
}

// LDS h-tile: [16 rows][256 cols] bf16, XOR-swizzled 16B slots (G4).
__device__ __forceinline__ int hoff(int row, int col){
  return (row*512 + col*2) ^ ((row & 7) << 4);
}
__device__ __forceinline__ void stH(short* buf, int row, int col, short v){
  *(short*)((char*)buf + hoff(row,col)) = v;
}
__device__ __forceinline__ short8 ldA(const short* buf, int k0, int lane){
  int row = lane & 15;
  int off = (row*512 + (k0 + ((lane>>4)<<3))*2) ^ ((row & 7) << 4);
  return *(const short8*)((const char*)buf + off);
}
// cpart C-fragment layout: per WG [s][w][g][lane*4 + r] bf16 (non-temporal)
__device__ __forceinline__ short* cpPtr(short* cp, int s, int w, int g, int lane){
  return cp + (((s*16 + w)*4 + g) << 8) + (lane << 2);
}
__device__ __forceinline__ f32x4 ldCP(const short* cp, int s, int w, int g, int lane){
  bf4 v = __builtin_nontemporal_load(
      (const bf4*)(cp + (((s*16 + w)*4 + g) << 8) + (lane << 2)));
  f32x4 r; r[0]=frombf(v[0]); r[1]=frombf(v[1]); r[2]=frombf(v[2]); r[3]=frombf(v[3]);
  return r;
}
// cell-state slices in global ws (non-temporal: keep L2 for weights)
__device__ __forceinline__ f32x4 ldCS(const float* b, int sl, int tid){
  return __builtin_nontemporal_load((const f32x4*)(b + sl*4096 + tid*4));
}
__device__ __forceinline__ void stCS(float* b, int sl, int tid, f32x4 v){
  __builtin_nontemporal_store(v, (f32x4*)(b + sl*4096 + tid*4));
}

// Register-path K=256 GEMM (depth-4) — used only in the rare tt==0 phases.
__device__ __forceinline__ void gemm256(f32x4 (&acc)[4], const short* __restrict__ W,
                                        int KT, int kt0, const short* __restrict__ A,
                                        int lane, int w){
  const short* w0 = W + (((     w)*KT + kt0)*64 + lane)*8;
  const short* w1 = W + (((16 + w)*KT + kt0)*64 + lane)*8;
  const short* w2 = W + (((32 + w)*KT + kt0)*64 + lane)*8;
  const short* w3 = W + (((48 + w)*KT + kt0)*64 + lane)*8;
  short8 b0[4], b1[4], b2[4], b3[4];
#define GLD(B,K) do{ (B)[0]=*(const short8*)(w0+(K)*512); (B)[1]=*(const short8*)(w1+(K)*512); \
                     (B)[2]=*(const short8*)(w2+(K)*512); (B)[3]=*(const short8*)(w3+(K)*512);}while(0)
#define GMM(B,K) do{ short8 a0_=ldA(A,(K)*32,lane); \
  acc[0]=MFMA16(a0_,(B)[0],acc[0]); acc[1]=MFMA16(a0_,(B)[1],acc[1]); \
  acc[2]=MFMA16(a0_,(B)[2],acc[2]); acc[3]=MFMA16(a0_,(B)[3],acc[3]);}while(0)
  GLD(b0,0); GLD(b1,1); GLD(b2,2); GLD(b3,3);
  GMM(b0,0); GLD(b0,4);
  GMM(b1,1); GLD(b1,5);
  GMM(b2,2); GLD(b2,6);
  GMM(b3,3); GLD(b3,7);
  GMM(b0,4);
  GMM(b1,5);
  GMM(b2,6);
  GMM(b3,7);
#undef GLD
#undef GMM
}

// LDS-staged K=256 GEMM segment via global_load_lds + counted vmcnt.
#define HST(B,H) do{ \
    const int kt_ = kt0 + ((H)>>1); \
    const int gb_ = ((H)&1)<<1; \
    GLOADLDS(Wb + ((((gb_    )*16 + w)*KT + kt_) << 9) + (lane<<3), \
             (char*)wb + (B)*32768 + (w<<11)); \
    GLOADLDS(Wb + ((((gb_ + 1)*16 + w)*KT + kt_) << 9) + (lane<<3), \
             (char*)wb + (B)*32768 + (w<<11) + 1024); \
  }while(0)
#define WAITH(H) do{ \
    if ((H) < 14)      { asm volatile("s_waitcnt vmcnt(4)" ::: "memory"); } \
    else if ((H) == 14){ asm volatile("s_waitcnt vmcnt(2)" ::: "memory"); } \
    else               { asm volatile("s_waitcnt vmcnt(0)" ::: "memory"); } \
    __builtin_amdgcn_sched_barrier(0); \
  }while(0)

__device__ __forceinline__ void gemmL(f32x4 (&acc)[4], const short* __restrict__ Wb,
                                      int KT, int kt0, const short* __restrict__ A,
                                      short* wb, int lane, int w){
  HST(0,0); HST(1,1); HST(2,2);
  #pragma unroll
  for (int h = 0; h < 16; ++h){
    WAITH(h);
    const int b = h % 3;
    const char* base = (const char*)wb + b*32768 + (w<<11) + (lane<<4);
    short8 t0 = *(const short8*)(base);
    short8 t1 = *(const short8*)(base + 1024);
    short8 a0_ = ldA(A, (h>>1)*32, lane);
    const int g0 = (h&1)<<1;
    acc[g0]   = MFMA16(a0_, t0, acc[g0]);
    acc[g0+1] = MFMA16(a0_, t1, acc[g0+1]);
    if (h < 13) HST((h+3)%3, h+3);
  }
}

// Dual variant: one weight stream, two A-matrices (C and D gates).
__device__ __forceinline__ void gemmL_dual(f32x4 (&acc)[4], f32x4 (&dacc)[4],
                                           const short* __restrict__ Wb,
                                           const short* __restrict__ A1,
                                           const short* __restrict__ A2,
                                           short* wb, int lane, int w){
  const int KT = 8, kt0 = 0;
  HST(0,0); HST(1,1); HST(2,2);
  #pragma unroll
  for (int h = 0; h < 16; ++h){
    WAITH(h);
    const int b = h % 3;
    const char* base = (const char*)wb + b*32768 + (w<<11) + (lane<<4);
    short8 t0 = *(const short8*)(base);
    short8 t1 = *(const short8*)(base + 1024);
    short8 a1_ = ldA(A1, (h>>1)*32, lane);
    short8 a2_ = ldA(A2, (h>>1)*32, lane);
    const int g0 = (h&1)<<1;
    acc[g0]    = MFMA16(a1_, t0, acc[g0]);
    dacc[g0]   = MFMA16(a2_, t0, dacc[g0]);
    acc[g0+1]  = MFMA16(a1_, t1, acc[g0+1]);
    dacc[g0+1] = MFMA16(a2_, t1, dacc[g0+1]);
    if (h < 13) HST((h+3)%3, h+3);
  }
}

// Pre-swizzle fp32 weight [N][K] slice into bf16 B-fragments
__global__ void swz_kernel(short* __restrict__ dst, const float* __restrict__ src,
                           int rowStride, int colOff, int Nreal,
                           int KTtot, int kt0, int ktN, int NT){
  int idx = blockIdx.x*256 + threadIdx.x;
  if (idx >= NT*ktN*512) return;
  int j = idx & 7, l = (idx>>3) & 63, tile = idx >> 9;
  int nt = tile / ktN, ktl = tile - nt*ktN;
  int n = nt*16 + (l & 15);
  int k = ktl*32 + ((l>>4)<<3) + j;
  float v = (n < Nreal) ? src[n*rowStride + colOff + k] : 0.f;
  dst[(((nt*KTtot + kt0 + ktl)*64 + l)<<3) + j] = tobf(v);
}

// eprojb layout: [s][v][col 0..255][gate 0..3] bf16
__global__ __launch_bounds__(1024) void eproj_kernel(
    const float* __restrict__ emb, const float* __restrict__ b1_ih,
    const float* __restrict__ b1_hh, const short* __restrict__ W1ihA_s,
    short* __restrict__ eprojb){
  __shared__ short es[36864];
  const int s = blockIdx.x;
  const int tid = threadIdx.x, lane = tid & 63, w = tid >> 6;
  const int l15 = lane & 15, lg = lane >> 4;
  for (int idx = tid; idx < 36864; idx += 1024){
    int row = idx >> 8, c2 = idx & 255;
    float v = (row < 130) ? emb[(s*130 + row)*256 + c2] : 0.f;
    *(short*)((char*)es + ((row*512 + c2*2) ^ ((row & 7) << 4))) = tobf(v);
  }
  __syncthreads();
  f32x4 z4 = {0.f,0.f,0.f,0.f};
  for (int rt = 0; rt < 9; ++rt){
    const short* Arow = es + rt*4096;
    f32x4 acc[4] = {z4, z4, z4, z4};
    #pragma unroll 2
    for (int kt = 0; kt < 8; ++kt){
      short8 a = ldA(Arow, kt*32, lane);
      #pragma unroll
      for (int q = 0; q < 4; ++q){
        short8 b = *(const short8*)(W1ihA_s + s*262144 + (((w*4+q)*8 + kt)*64 + lane)*8);
        acc[q] = MFMA16(a, b, acc[q]);
      }
    }
    #pragma unroll
    for (int q = 0; q < 4; ++q)
      #pragma unroll
      for (int r = 0; r < 4; ++r){
        int v = rt*16 + lg*4 + r;
        if (v < 130){
          int gc = (w*4 + q)*16 + l15;
          eprojb[(s*130 + v)*1024 + ((gc & 255) << 2) + (gc >> 8)] =
            tobf(acc[q][r] + b1_ih[s*1024 + gc] + b1_hh[s*1024 + gc]);
        }
      }
  }
}

// Main persistent kernel: r19 structure + non-temporal state/output traffic.
__global__ __launch_bounds__(1024)
__attribute__((amdgpu_waves_per_eu(4,4))) void rnn_main(
    const float* __restrict__ cbuf, const int* __restrict__ tgt,
    const float* __restrict__ b_hid, const float* __restrict__ b1_ih,
    const float* __restrict__ b1_hh, const float* __restrict__ bc_ih,
    const float* __restrict__ bc_hh, const float* __restrict__ boutp,
    const short* __restrict__ eprojb, short* __restrict__ cpart,
    float* __restrict__ cst,
    const short* __restrict__ W1hh_s, const short* __restrict__ W1ihA_s,
    const short* __restrict__ W1ihB_s, const short* __restrict__ Wc_s,
    const short* __restrict__ Whid_s, const short* __restrict__ Wout_s,
    float* __restrict__ outp)
{
  __shared__ short h1b[3*4096];
  __shared__ short h2b[3*4096];
  __shared__ short hcb[4096];
  __shared__ short wbuf[49152];   // 3 x 32KB half-chunk staging buffers

  const int tid  = threadIdx.x;
  const int lane = tid & 63;
  const int w    = tid >> 6;      // wave 0..15
  const int l15  = lane & 15;
  const int lg   = lane >> 4;
  const int chunk = blockIdx.x;   // 0..7
  const int bar   = blockIdx.y;   // 0..15
  const int b0    = chunk * 16;
  const int cc    = w*16 + l15;
  const int wgid  = bar*8 + chunk;

  short* cpWG  = cpart + wgid*49152;
  float* cstWG = cst + (size_t)wgid*28672;   // 7 slices: 0-2 c1, 3-5 c2, 6 cc
  const f32x4 z4 = {0.f,0.f,0.f,0.f};

  #pragma unroll 1
  for (int tt = 0; tt < 16; ++tt){
    const int t = bar*16 + tt;

    if (tt == 0){
      for (int idx = tid; idx < 4096; idx += 1024){
        int row = idx >> 8, c2 = idx & 255;
        stH(h2b,        row, c2, tobf(cbuf[((b0+row)*17 + bar)*256 + c2]));
        stH(h2b + 4096, row, c2, tobf(cbuf[((b0+row)*17 + bar + 1)*256 + c2]));
      }
      __syncthreads();
      f32x4 hi0 = z4;
      #pragma unroll
      for (int kt = 0; kt < 8; ++kt){
        short8 a0 = ldA(h2b, kt*32, lane);
        short8 bb = *(const short8*)(Whid_s + ((w*8 + kt)*64 + lane)*8);
        hi0 = MFMA16(a0, bb, hi0);
      }
      #pragma unroll 1
      for (int s = 0; s < 3; ++s){
        f32x4 acc[4] = {z4, z4, z4, z4};
        gemm256(acc, W1ihB_s + s*262144, 8, 0, h2b + 4096, lane, w);
        #pragma unroll
        for (int g = 0; g < 4; ++g)
          __builtin_nontemporal_store(pack4(acc[g]), (bf4*)cpPtr(cpWG, s, w, g, lane));
      }
      __syncthreads();
      {
        float bh = b_hid[cc];
        #pragma unroll
        for (int r = 0; r < 4; ++r){
          int row = lg*4 + r;
          short hv = tobf(tanhf_(hi0[r] + bh));
          stH(h1b,       row,cc,hv); stH(h1b+4096, row,cc,hv); stH(h1b+8192,row,cc,hv);
          stH(h2b,       row,cc,hv); stH(h2b+4096, row,cc,hv); stH(h2b+8192,row,cc,hv);
          stH(hcb,       row,cc,hv);
        }
      }
      __syncthreads();
    }

    // ---------- Stage A: per-stream; elem(s) overlaps gemm(s+1) ----------
    #pragma unroll 1
    for (int s = 0; s < 3; ++s){
      f32x4 cold = tt ? ldCS(cstWG, s, tid) : z4;
      f32x4 acc[4];
      #pragma unroll
      for (int g = 0; g < 4; ++g) acc[g] = ldCP(cpWG, s, w, g, lane);
      gemmL(acc, W1hh_s + s*262144, 8, 0, h1b + s*4096, wbuf, lane, w);
      __syncthreads();   // protect h1b[s] read-before-write
      f32x4 cnew;
      #pragma unroll
      for (int r = 0; r < 4; ++r){
        const int row = lg*4 + r;
        const int tok = (t == 0) ? 0 : tgt[(s*128 + b0 + row)*256 + (t-1)];
        bf4 e4 = *(const bf4*)(eprojb + (size_t)(s*130 + tok)*1024 + cc*4);
        float pi = acc[0][r] + frombf(e4[0]);
        float pf = acc[1][r] + frombf(e4[1]);
        float pg = acc[2][r] + frombf(e4[2]);
        float po = acc[3][r] + frombf(e4[3]);
        float cs = sigf(pf)*cold[r] + sigf(pi)*tanhf_(pg);
        cnew[r] = cs;
        stH(h1b + s*4096, row, cc, tobf(sigf(po)*tanhf_(cs)));
      }
      stCS(cstWG, s, tid, cnew);
    }
    __syncthreads();     // h1b[0..2] complete before B reads them

    // ---------- per-stream sequential section ----------
    #pragma unroll 1
    for (int i = 0; i < 3; ++i){
      // ---- Bg: context lstm_c GEMM (K=1024 forward over [h1_0,h1_1,h1_2,hc])
      {
        f32x4 cold = (tt == 0 && i == 0) ? z4 : ldCS(cstWG, 6, tid);
        f32x4 acc[4] = {z4, z4, z4, z4};
        #pragma unroll 1
        for (int seg = 0; seg < 4; ++seg){
          const short* Ax = (seg==0) ? h1b : (seg==1) ? (h1b+4096)
                           : (seg==2) ? (h1b+8192) : hcb;
          gemmL(acc, Wc_s, 32, seg*8, Ax, wbuf, lane, w);
        }
        __syncthreads();
        const float bi = bc_ih[cc]      + bc_hh[cc];
        const float bf = bc_ih[256+cc]  + bc_hh[256+cc];
        const float bg = bc_ih[512+cc]  + bc_hh[512+cc];
        const float bo = bc_ih[768+cc]  + bc_hh[768+cc];
        f32x4 cnew;
        #pragma unroll
        for (int r = 0; r < 4; ++r){
          const int row = lg*4 + r;
          float cs = sigf(acc[1][r] + bf)*cold[r]
                   + sigf(acc[0][r] + bi)*tanhf_(acc[2][r] + bg);
          cnew[r] = cs;
          stH(hcb, row, cc, tobf(sigf(acc[3][r] + bo)*tanhf_(cs)));
        }
        stCS(cstWG, 6, tid, cnew);
        __syncthreads();
      }
      // ---- CDg: fused lstm2 + D GEMM over one shared W1hh stream
      f32x4 dacc[4];
      {
        f32x4 cold = (tt == 0) ? z4 : ldCS(cstWG, 3+i, tid);
        f32x4 acc[4];
        #pragma unroll
        for (int g = 0; g < 4; ++g){ acc[g] = ldCP(cpWG, i, w, g, lane); dacc[g] = acc[g]; }
        gemmL(acc, W1ihA_s + i*262144, 8, 0, hcb, wbuf, lane, w);
        gemmL_dual(acc, dacc, W1hh_s + i*262144, h2b + i*4096, h1b + i*4096, wbuf, lane, w);
        __syncthreads();
        const float bi = b1_ih[i*1024+cc]      + b1_hh[i*1024+cc];
        const float bf = b1_ih[i*1024+256+cc]  + b1_hh[i*1024+256+cc];
        const float bg = b1_ih[i*1024+512+cc]  + b1_hh[i*1024+512+cc];
        const float bo = b1_ih[i*1024+768+cc]  + b1_hh[i*1024+768+cc];
        f32x4 cnew;
        #pragma unroll
        for (int r = 0; r < 4; ++r){
          const int row = lg*4 + r;
          float cs = sigf(acc[1][r] + bf)*cold[r]
                   + sigf(acc[0][r] + bi)*tanhf_(acc[2][r] + bg);
          cnew[r] = cs;
          stH(h2b + i*4096, row, cc, tobf(sigf(acc[3][r] + bo)*tanhf_(cs)));
        }
        stCS(cstWG, 3+i, tid, cnew);
        __syncthreads();
      }
      // ---- Eg: (h1+h2_new)@Wout, then DEe using dacc
      {
        f32x4 cold = ldCS(cstWG, i, tid);
        f32x4 e0 = z4;
        const short* h1p = h1b + i*4096;
        const short* h2p = h2b + i*4096;
        if (w < 9){
          const short* wo = Wout_s + i*36864 + ((w*8)*64 + lane)*8;
          short8 ebA = *(const short8*)(wo);
          short8 ebB = *(const short8*)(wo + 512);
#define EMM(EB,K) do{ short8 a_=ldA(h1p,(K)*32,lane), f_=ldA(h2p,(K)*32,lane); \
  e0 = MFMA16(a_,(EB),e0); e0 = MFMA16(f_,(EB),e0); }while(0)
          EMM(ebA,0); ebA = *(const short8*)(wo + 2*512);
          EMM(ebB,1); ebB = *(const short8*)(wo + 3*512);
          EMM(ebA,2); ebA = *(const short8*)(wo + 4*512);
          EMM(ebB,3); ebB = *(const short8*)(wo + 5*512);
          EMM(ebA,4); ebA = *(const short8*)(wo + 6*512);
          EMM(ebB,5); ebB = *(const short8*)(wo + 7*512);
          EMM(ebA,6);
          EMM(ebB,7);
#undef EMM
        }
        __syncthreads();   // E reads h1b[i] complete before DEe writes it
        f32x4 cnew;
        #pragma unroll
        for (int r = 0; r < 4; ++r){
          const int row = lg*4 + r;
          const int tok = tgt[(i*128 + b0 + row)*256 + t];
          bf4 e4 = *(const bf4*)(eprojb + (size_t)(i*130 + tok)*1024 + cc*4);
          float pi = dacc[0][r] + frombf(e4[0]);
          float pf = dacc[1][r] + frombf(e4[1]);
          float pg = dacc[2][r] + frombf(e4[2]);
          float po = dacc[3][r] + frombf(e4[3]);
          float cs = sigf(pf)*cold[r] + sigf(pi)*tanhf_(pg);
          cnew[r] = cs;
          stH(h1b + i*4096, row, cc, tobf(sigf(po)*tanhf_(cs)));
        }
        stCS(cstWG, i, tid, cnew);
        if (w < 8){
          const int v = w*16 + l15;
          const float bo = boutp[i*130 + v];
          #pragma unroll
          for (int r = 0; r < 4; ++r){
            const int row = lg*4 + r;
            __builtin_nontemporal_store(e0[r] + bo,
              &outp[(size_t)((i*128 + b0 + row)*256 + t)*130 + v]);
          }
        } else if (w == 8 && l15 < 2){
          const int v = 128 + l15;
          const float bo = boutp[i*130 + v];
          #pragma unroll
          for (int r = 0; r < 4; ++r){
            const int row = lg*4 + r;
            __builtin_nontemporal_store(e0[r] + bo,
              &outp[(size_t)((i*128 + b0 + row)*256 + t)*130 + v]);
          }
        }
        __syncthreads();
      }
    } // i
  } // tt
}

extern "C" void kernel_launch(void* const* d_in, const int* in_sizes, int n_in,
                              void* d_out, int out_size, void* d_ws, size_t ws_size,
                              hipStream_t stream){
  (void)in_sizes; (void)n_in; (void)out_size; (void)ws_size;
  const float* c     = (const float*)d_in[0];
  const int*   tgt   = (const int*)  d_in[1];
  const float* W_hid = (const float*)d_in[3];
  const float* b_hid = (const float*)d_in[4];
  const float* W1_ih = (const float*)d_in[5];
  const float* W1_hh = (const float*)d_in[6];
  const float* b1_ih = (const float*)d_in[7];
  const float* b1_hh = (const float*)d_in[8];
  const float* Wc_ih = (const float*)d_in[9];
  const float* Wc_hh = (const float*)d_in[10];
  const float* bc_ih = (const float*)d_in[11];
  const float* bc_hh = (const float*)d_in[12];
  const float* emb   = (const float*)d_in[13];
  const float* Wout  = (const float*)d_in[14];
  const float* bout  = (const float*)d_in[15];
  float* outp = (float*)d_out;

  short* ws = (short*)d_ws;
  short* W1hh_s  = ws;                 // 3 x 64nt x 8kt tiles
  short* W1ihA_s = ws + 786432;        // W1_ih[:, :256]
  short* W1ihB_s = ws + 1572864;       // W1_ih[:, 256:512]
  short* Wc_s    = ws + 2359296;       // [64nt][32kt]: ih k<768, hh k>=768
  short* Whid_s  = ws + 3407872;       // [256][256]
  short* Wout_s  = ws + 3473408;       // 3 x [144 pad][256]
  short* eprojb  = ws + 3584000;       // [3][130][256][4] bf16
  short* cpart   = ws + 3983360;       // [128 WG][3][16][4][256] bf16 C-frags
  float* cstate  = (float*)((char*)d_ws + 20549632);  // [128 WG][7][1024] f32x4

  for (int s = 0; s < 3; ++s){
    swz_kernel<<<1024,256,0,stream>>>(W1hh_s  + s*262144, W1_hh + s*262144, 256,   0, 1024,  8, 0,  8, 64);
    swz_kernel<<<1024,256,0,stream>>>(W1ihA_s + s*262144, W1_ih + s*524288, 512,   0, 1024,  8, 0,  8, 64);
    swz_kernel<<<1024,256,0,stream>>>(W1ihB_s + s*262144, W1_ih + s*524288, 512, 256, 1024,  8, 0,  8, 64);
    swz_kernel<<< 144,256,0,stream>>>(Wout_s  + s*36864,  Wout  + s*33280,  256,   0,  130,  8, 0,  8,  9);
  }
  swz_kernel<<<3072,256,0,stream>>>(Wc_s,   Wc_ih, 768, 0, 1024, 32,  0, 24, 64);
  swz_kernel<<<1024,256,0,stream>>>(Wc_s,   Wc_hh, 256, 0, 1024, 32, 24,  8, 64);
  swz_kernel<<< 256,256,0,stream>>>(Whid_s, W_hid, 256, 0,  512,  8,  0,  8, 16);
  eproj_kernel<<<3,1024,0,stream>>>(emb, b1_ih, b1_hh, W1ihA_s, eprojb);

  rnn_main<<<dim3(8,16),1024,0,stream>>>(c, tgt, b_hid, b1_ih, b1_hh, bc_ih, bc_hh,
                                         bout, eprojb, cpart, cstate,
                                         W1hh_s, W1ihA_s, W1ihB_s,
                                         Wc_s, Whid_s, Wout_s, outp);
}

// Round 23
// 2639.991 us; speedup vs baseline: 1.0092x; 1.0092x over previous
//
#include <hip/hip_runtime.h>
#include <hip/hip_bf16.h>

typedef float  f32x4  __attribute__((ext_vector_type(4)));
typedef short  short8 __attribute__((ext_vector_type(8)));
typedef short  bf4    __attribute__((ext_vector_type(4)));

#define MFMA16(a,b,c) __builtin_amdgcn_mfma_f32_16x16x32_bf16((a),(b),(c),0,0,0)
#define GLOADLDS(SRC, DST) __builtin_amdgcn_global_load_lds( \
  (const __attribute__((address_space(1))) void*)(SRC), \
  (__attribute__((address_space(3))) void*)(DST), 16, 0, 0)

__device__ __forceinline__ short tobf(float f){
  unsigned u = __float_as_uint(f);
  u += 0x7fffu + ((u >> 16) & 1u);
  return (short)(u >> 16);
}
__device__ __forceinline__ float frombf(short s){
  return __uint_as_float(((unsigned)(unsigned short)s) << 16);
}
__device__ __forceinline__ float sigf(float x){
  return 1.f / (1.f + __expf(-x));
}
__device__ __forceinline__ float tanhf_(float x){
  float ax = fabsf(x);
  float e  = __expf(-2.f * ax);
  float t  = (1.f - e) / (1.f + e);
  return x >= 0.f ? t : -t;
}
__device__ __forceinline__ bf4 pack4(f32x4 v){
  bf4 r; r[0]=tobf(v[0]); r[1]=tobf(v[1]); r[2]=tobf(v[2]); r[3]=tobf(v[3]); return r;
}

// LDS h-tile: [16 rows][256 cols] bf16, XOR-swizzled 16B slots (G4).
__device__ __forceinline__ int hoff(int row, int col){
  return (row*512 + col*2) ^ ((row & 7) << 4);
}
__device__ __forceinline__ void stH(short* buf, int row, int col, short v){
  *(short*)((char*)buf + hoff(row,col)) = v;
}
__device__ __forceinline__ short8 ldA(const short* buf, int k0, int lane){
  int row = lane & 15;
  int off = (row*512 + (k0 + ((lane>>4)<<3))*2) ^ ((row & 7) << 4);
  return *(const short8*)((const char*)buf + off);
}
// cpart C-fragment layout: per WG [s][w][g][lane*4 + r] bf16
__device__ __forceinline__ short* cpPtr(short* cp, int s, int w, int g, int lane){
  return cp + (((s*16 + w)*4 + g) << 8) + (lane << 2);
}
__device__ __forceinline__ f32x4 ldCP(const short* cp, int s, int w, int g, int lane){
  bf4 v = *(const bf4*)(cp + (((s*16 + w)*4 + g) << 8) + (lane << 2));
  f32x4 r; r[0]=frombf(v[0]); r[1]=frombf(v[1]); r[2]=frombf(v[2]); r[3]=frombf(v[3]);
  return r;
}
// cell-state slices in global ws: per WG 7 slices x 1024 threads x f32x4
__device__ __forceinline__ f32x4 ldCS(const float* b, int sl, int tid){
  return *(const f32x4*)(b + sl*4096 + tid*4);
}
__device__ __forceinline__ void stCS(float* b, int sl, int tid, f32x4 v){
  *(f32x4*)(b + sl*4096 + tid*4) = v;
}

// Register-path K=256 GEMM (depth-4) — used only in the rare tt==0 phases.
__device__ __forceinline__ void gemm256(f32x4 (&acc)[4], const short* __restrict__ W,
                                        int KT, int kt0, const short* __restrict__ A,
                                        int lane, int w){
  const short* w0 = W + (((     w)*KT + kt0)*64 + lane)*8;
  const short* w1 = W + (((16 + w)*KT + kt0)*64 + lane)*8;
  const short* w2 = W + (((32 + w)*KT + kt0)*64 + lane)*8;
  const short* w3 = W + (((48 + w)*KT + kt0)*64 + lane)*8;
  short8 b0[4], b1[4], b2[4], b3[4];
#define GLD(B,K) do{ (B)[0]=*(const short8*)(w0+(K)*512); (B)[1]=*(const short8*)(w1+(K)*512); \
                     (B)[2]=*(const short8*)(w2+(K)*512); (B)[3]=*(const short8*)(w3+(K)*512);}while(0)
#define GMM(B,K) do{ short8 a0_=ldA(A,(K)*32,lane); \
  acc[0]=MFMA16(a0_,(B)[0],acc[0]); acc[1]=MFMA16(a0_,(B)[1],acc[1]); \
  acc[2]=MFMA16(a0_,(B)[2],acc[2]); acc[3]=MFMA16(a0_,(B)[3],acc[3]);}while(0)
  GLD(b0,0); GLD(b1,1); GLD(b2,2); GLD(b3,3);
  GMM(b0,0); GLD(b0,4);
  GMM(b1,1); GLD(b1,5);
  GMM(b2,2); GLD(b2,6);
  GMM(b3,3); GLD(b3,7);
  GMM(b0,4);
  GMM(b1,5);
  GMM(b2,6);
  GMM(b3,7);
#undef GLD
#undef GMM
}

// LDS-staged K=256 GEMM segment via global_load_lds + counted vmcnt.
// Wave-private staging: wave w stages its 4 gate tiles per kt-chunk as two
// half-chunks (2 tiles = 2KB) into a 3-deep ring of LDS buffers. No barriers;
// vmcnt(N) gates consumption (never 0 until the tail). 16 half-stages/segment.
#define HST(B,H) do{ \
    const int kt_ = kt0 + ((H)>>1); \
    const int gb_ = ((H)&1)<<1; \
    GLOADLDS(Wb + ((((gb_    )*16 + w)*KT + kt_) << 9) + (lane<<3), \
             (char*)wb + (B)*32768 + (w<<11)); \
    GLOADLDS(Wb + ((((gb_ + 1)*16 + w)*KT + kt_) << 9) + (lane<<3), \
             (char*)wb + (B)*32768 + (w<<11) + 1024); \
  }while(0)
#define WAITH(H) do{ \
    if ((H) < 14)      { asm volatile("s_waitcnt vmcnt(4)" ::: "memory"); } \
    else if ((H) == 14){ asm volatile("s_waitcnt vmcnt(2)" ::: "memory"); } \
    else               { asm volatile("s_waitcnt vmcnt(0)" ::: "memory"); } \
    __builtin_amdgcn_sched_barrier(0); \
  }while(0)

__device__ __forceinline__ void gemmL(f32x4 (&acc)[4], const short* __restrict__ Wb,
                                      int KT, int kt0, const short* __restrict__ A,
                                      short* wb, int lane, int w){
  HST(0,0); HST(1,1); HST(2,2);
  #pragma unroll
  for (int h = 0; h < 16; ++h){
    WAITH(h);
    const int b = h % 3;
    const char* base = (const char*)wb + b*32768 + (w<<11) + (lane<<4);
    short8 t0 = *(const short8*)(base);
    short8 t1 = *(const short8*)(base + 1024);
    short8 a0_ = ldA(A, (h>>1)*32, lane);
    const int g0 = (h&1)<<1;
    acc[g0]   = MFMA16(a0_, t0, acc[g0]);
    acc[g0+1] = MFMA16(a0_, t1, acc[g0+1]);
    if (h < 13) HST((h+3)%3, h+3);
  }
}

// Dual variant: one weight stream, two A-matrices (C and D gates).
__device__ __forceinline__ void gemmL_dual(f32x4 (&acc)[4], f32x4 (&dacc)[4],
                                           const short* __restrict__ Wb,
                                           const short* __restrict__ A1,
                                           const short* __restrict__ A2,
                                           short* wb, int lane, int w){
  const int KT = 8, kt0 = 0;
  HST(0,0); HST(1,1); HST(2,2);
  #pragma unroll
  for (int h = 0; h < 16; ++h){
    WAITH(h);
    const int b = h % 3;
    const char* base = (const char*)wb + b*32768 + (w<<11) + (lane<<4);
    short8 t0 = *(const short8*)(base);
    short8 t1 = *(const short8*)(base + 1024);
    short8 a1_ = ldA(A1, (h>>1)*32, lane);
    short8 a2_ = ldA(A2, (h>>1)*32, lane);
    const int g0 = (h&1)<<1;
    acc[g0]    = MFMA16(a1_, t0, acc[g0]);
    dacc[g0]   = MFMA16(a2_, t0, dacc[g0]);
    acc[g0+1]  = MFMA16(a1_, t1, acc[g0+1]);
    dacc[g0+1] = MFMA16(a2_, t1, dacc[g0+1]);
    if (h < 13) HST((h+3)%3, h+3);
  }
}

// Pre-swizzle fp32 weight [N][K] slice into bf16 B-fragments
__global__ void swz_kernel(short* __restrict__ dst, const float* __restrict__ src,
                           int rowStride, int colOff, int Nreal,
                           int KTtot, int kt0, int ktN, int NT){
  int idx = blockIdx.x*256 + threadIdx.x;
  if (idx >= NT*ktN*512) return;
  int j = idx & 7, l = (idx>>3) & 63, tile = idx >> 9;
  int nt = tile / ktN, ktl = tile - nt*ktN;
  int n = nt*16 + (l & 15);
  int k = ktl*32 + ((l>>4)<<3) + j;
  float v = (n < Nreal) ? src[n*rowStride + colOff + k] : 0.f;
  dst[(((nt*KTtot + kt0 + ktl)*64 + l)<<3) + j] = tobf(v);
}

// eprojb layout: [s][v][col 0..255][gate 0..3] bf16
__global__ __launch_bounds__(1024) void eproj_kernel(
    const float* __restrict__ emb, const float* __restrict__ b1_ih,
    const float* __restrict__ b1_hh, const short* __restrict__ W1ihA_s,
    short* __restrict__ eprojb){
  __shared__ short es[36864];
  const int s = blockIdx.x;
  const int tid = threadIdx.x, lane = tid & 63, w = tid >> 6;
  const int l15 = lane & 15, lg = lane >> 4;
  for (int idx = tid; idx < 36864; idx += 1024){
    int row = idx >> 8, c2 = idx & 255;
    float v = (row < 130) ? emb[(s*130 + row)*256 + c2] : 0.f;
    *(short*)((char*)es + ((row*512 + c2*2) ^ ((row & 7) << 4))) = tobf(v);
  }
  __syncthreads();
  f32x4 z4 = {0.f,0.f,0.f,0.f};
  for (int rt = 0; rt < 9; ++rt){
    const short* Arow = es + rt*4096;
    f32x4 acc[4] = {z4, z4, z4, z4};
    #pragma unroll 2
    for (int kt = 0; kt < 8; ++kt){
      short8 a = ldA(Arow, kt*32, lane);
      #pragma unroll
      for (int q = 0; q < 4; ++q){
        short8 b = *(const short8*)(W1ihA_s + s*262144 + (((w*4+q)*8 + kt)*64 + lane)*8);
        acc[q] = MFMA16(a, b, acc[q]);
      }
    }
    #pragma unroll
    for (int q = 0; q < 4; ++q)
      #pragma unroll
      for (int r = 0; r < 4; ++r){
        int v = rt*16 + lg*4 + r;
        if (v < 130){
          int gc = (w*4 + q)*16 + l15;
          eprojb[(s*130 + v)*1024 + ((gc & 255) << 2) + (gc >> 8)] =
            tobf(acc[q][r] + b1_ih[s*1024 + gc] + b1_hh[s*1024 + gc]);
        }
      }
  }
}

// Main persistent kernel: round-18 structure, weight streams moved to the
// LDS-staged counted-vmcnt pipeline (gemmL / gemmL_dual). Best-known config.
__global__ __launch_bounds__(1024)
__attribute__((amdgpu_waves_per_eu(4,4))) void rnn_main(
    const float* __restrict__ cbuf, const int* __restrict__ tgt,
    const float* __restrict__ b_hid, const float* __restrict__ b1_ih,
    const float* __restrict__ b1_hh, const float* __restrict__ bc_ih,
    const float* __restrict__ bc_hh, const float* __restrict__ boutp,
    const short* __restrict__ eprojb, short* __restrict__ cpart,
    float* __restrict__ cst,
    const short* __restrict__ W1hh_s, const short* __restrict__ W1ihA_s,
    const short* __restrict__ W1ihB_s, const short* __restrict__ Wc_s,
    const short* __restrict__ Whid_s, const short* __restrict__ Wout_s,
    float* __restrict__ outp)
{
  __shared__ short h1b[3*4096];
  __shared__ short h2b[3*4096];
  __shared__ short hcb[4096];
  __shared__ short wbuf[49152];   // 3 x 32KB half-chunk staging buffers

  const int tid  = threadIdx.x;
  const int lane = tid & 63;
  const int w    = tid >> 6;      // wave 0..15
  const int l15  = lane & 15;
  const int lg   = lane >> 4;
  const int chunk = blockIdx.x;   // 0..7
  const int bar   = blockIdx.y;   // 0..15
  const int b0    = chunk * 16;
  const int cc    = w*16 + l15;
  const int wgid  = bar*8 + chunk;

  short* cpWG  = cpart + wgid*49152;
  float* cstWG = cst + (size_t)wgid*28672;   // 7 slices: 0-2 c1, 3-5 c2, 6 cc
  const f32x4 z4 = {0.f,0.f,0.f,0.f};

  #pragma unroll 1
  for (int tt = 0; tt < 16; ++tt){
    const int t = bar*16 + tt;

    if (tt == 0){
      for (int idx = tid; idx < 4096; idx += 1024){
        int row = idx >> 8, c2 = idx & 255;
        stH(h2b,        row, c2, tobf(cbuf[((b0+row)*17 + bar)*256 + c2]));
        stH(h2b + 4096, row, c2, tobf(cbuf[((b0+row)*17 + bar + 1)*256 + c2]));
      }
      __syncthreads();
      f32x4 hi0 = z4;
      #pragma unroll
      for (int kt = 0; kt < 8; ++kt){
        short8 a0 = ldA(h2b, kt*32, lane);
        short8 bb = *(const short8*)(Whid_s + ((w*8 + kt)*64 + lane)*8);
        hi0 = MFMA16(a0, bb, hi0);
      }
      #pragma unroll 1
      for (int s = 0; s < 3; ++s){
        f32x4 acc[4] = {z4, z4, z4, z4};
        gemm256(acc, W1ihB_s + s*262144, 8, 0, h2b + 4096, lane, w);
        #pragma unroll
        for (int g = 0; g < 4; ++g)
          *(bf4*)cpPtr(cpWG, s, w, g, lane) = pack4(acc[g]);
      }
      __syncthreads();
      {
        float bh = b_hid[cc];
        #pragma unroll
        for (int r = 0; r < 4; ++r){
          int row = lg*4 + r;
          short hv = tobf(tanhf_(hi0[r] + bh));
          stH(h1b,       row,cc,hv); stH(h1b+4096, row,cc,hv); stH(h1b+8192,row,cc,hv);
          stH(h2b,       row,cc,hv); stH(h2b+4096, row,cc,hv); stH(h2b+8192,row,cc,hv);
          stH(hcb,       row,cc,hv);
        }
      }
      __syncthreads();
    }

    // ---------- Stage A: per-stream; elem(s) overlaps gemm(s+1) ----------
    #pragma unroll 1
    for (int s = 0; s < 3; ++s){
      f32x4 cold = tt ? ldCS(cstWG, s, tid) : z4;
      f32x4 acc[4];
      #pragma unroll
      for (int g = 0; g < 4; ++g) acc[g] = ldCP(cpWG, s, w, g, lane);
      gemmL(acc, W1hh_s + s*262144, 8, 0, h1b + s*4096, wbuf, lane, w);
      __syncthreads();   // protect h1b[s] read-before-write
      f32x4 cnew;
      #pragma unroll
      for (int r = 0; r < 4; ++r){
        const int row = lg*4 + r;
        const int tok = (t == 0) ? 0 : tgt[(s*128 + b0 + row)*256 + (t-1)];
        bf4 e4 = *(const bf4*)(eprojb + (size_t)(s*130 + tok)*1024 + cc*4);
        float pi = acc[0][r] + frombf(e4[0]);
        float pf = acc[1][r] + frombf(e4[1]);
        float pg = acc[2][r] + frombf(e4[2]);
        float po = acc[3][r] + frombf(e4[3]);
        float cs = sigf(pf)*cold[r] + sigf(pi)*tanhf_(pg);
        cnew[r] = cs;
        stH(h1b + s*4096, row, cc, tobf(sigf(po)*tanhf_(cs)));
      }
      stCS(cstWG, s, tid, cnew);
    }
    __syncthreads();     // h1b[0..2] complete before B reads them

    // ---------- per-stream sequential section ----------
    #pragma unroll 1
    for (int i = 0; i < 3; ++i){
      // ---- Bg: context lstm_c GEMM (K=1024 forward over [h1_0,h1_1,h1_2,hc])
      {
        f32x4 cold = (tt == 0 && i == 0) ? z4 : ldCS(cstWG, 6, tid);
        f32x4 acc[4] = {z4, z4, z4, z4};
        #pragma unroll 1
        for (int seg = 0; seg < 4; ++seg){
          const short* Ax = (seg==0) ? h1b : (seg==1) ? (h1b+4096)
                           : (seg==2) ? (h1b+8192) : hcb;
          gemmL(acc, Wc_s, 32, seg*8, Ax, wbuf, lane, w);
        }
        __syncthreads();
        const float bi = bc_ih[cc]      + bc_hh[cc];
        const float bf = bc_ih[256+cc]  + bc_hh[256+cc];
        const float bg = bc_ih[512+cc]  + bc_hh[512+cc];
        const float bo = bc_ih[768+cc]  + bc_hh[768+cc];
        f32x4 cnew;
        #pragma unroll
        for (int r = 0; r < 4; ++r){
          const int row = lg*4 + r;
          float cs = sigf(acc[1][r] + bf)*cold[r]
                   + sigf(acc[0][r] + bi)*tanhf_(acc[2][r] + bg);
          cnew[r] = cs;
          stH(hcb, row, cc, tobf(sigf(acc[3][r] + bo)*tanhf_(cs)));
        }
        stCS(cstWG, 6, tid, cnew);
        __syncthreads();
      }
      // ---- CDg: fused lstm2 + D GEMM over one shared W1hh stream
      f32x4 dacc[4];
      {
        f32x4 cold = (tt == 0) ? z4 : ldCS(cstWG, 3+i, tid);
        f32x4 acc[4];
        #pragma unroll
        for (int g = 0; g < 4; ++g){ acc[g] = ldCP(cpWG, i, w, g, lane); dacc[g] = acc[g]; }
        gemmL(acc, W1ihA_s + i*262144, 8, 0, hcb, wbuf, lane, w);
        gemmL_dual(acc, dacc, W1hh_s + i*262144, h2b + i*4096, h1b + i*4096, wbuf, lane, w);
        __syncthreads();
        const float bi = b1_ih[i*1024+cc]      + b1_hh[i*1024+cc];
        const float bf = b1_ih[i*1024+256+cc]  + b1_hh[i*1024+256+cc];
        const float bg = b1_ih[i*1024+512+cc]  + b1_hh[i*1024+512+cc];
        const float bo = b1_ih[i*1024+768+cc]  + b1_hh[i*1024+768+cc];
        f32x4 cnew;
        #pragma unroll
        for (int r = 0; r < 4; ++r){
          const int row = lg*4 + r;
          float cs = sigf(acc[1][r] + bf)*cold[r]
                   + sigf(acc[0][r] + bi)*tanhf_(acc[2][r] + bg);
          cnew[r] = cs;
          stH(h2b + i*4096, row, cc, tobf(sigf(acc[3][r] + bo)*tanhf_(cs)));
        }
        stCS(cstWG, 3+i, tid, cnew);
        __syncthreads();
      }
      // ---- Eg: (h1+h2_new)@Wout, then DEe using dacc
      {
        f32x4 cold = ldCS(cstWG, i, tid);
        f32x4 e0 = z4;
        const short* h1p = h1b + i*4096;
        const short* h2p = h2b + i*4096;
        if (w < 9){
          const short* wo = Wout_s + i*36864 + ((w*8)*64 + lane)*8;
          short8 ebA = *(const short8*)(wo);
          short8 ebB = *(const short8*)(wo + 512);
#define EMM(EB,K) do{ short8 a_=ldA(h1p,(K)*32,lane), f_=ldA(h2p,(K)*32,lane); \
  e0 = MFMA16(a_,(EB),e0); e0 = MFMA16(f_,(EB),e0); }while(0)
          EMM(ebA,0); ebA = *(const short8*)(wo + 2*512);
          EMM(ebB,1); ebB = *(const short8*)(wo + 3*512);
          EMM(ebA,2); ebA = *(const short8*)(wo + 4*512);
          EMM(ebB,3); ebB = *(const short8*)(wo + 5*512);
          EMM(ebA,4); ebA = *(const short8*)(wo + 6*512);
          EMM(ebB,5); ebB = *(const short8*)(wo + 7*512);
          EMM(ebA,6);
          EMM(ebB,7);
#undef EMM
        }
        __syncthreads();   // E reads h1b[i] complete before DEe writes it
        f32x4 cnew;
        #pragma unroll
        for (int r = 0; r < 4; ++r){
          const int row = lg*4 + r;
          const int tok = tgt[(i*128 + b0 + row)*256 + t];
          bf4 e4 = *(const bf4*)(eprojb + (size_t)(i*130 + tok)*1024 + cc*4);
          float pi = dacc[0][r] + frombf(e4[0]);
          float pf = dacc[1][r] + frombf(e4[1]);
          float pg = dacc[2][r] + frombf(e4[2]);
          float po = dacc[3][r] + frombf(e4[3]);
          float cs = sigf(pf)*cold[r] + sigf(pi)*tanhf_(pg);
          cnew[r] = cs;
          stH(h1b + i*4096, row, cc, tobf(sigf(po)*tanhf_(cs)));
        }
        stCS(cstWG, i, tid, cnew);
        if (w < 8){
          const int v = w*16 + l15;
          const float bo = boutp[i*130 + v];
          #pragma unroll
          for (int r = 0; r < 4; ++r){
            const int row = lg*4 + r;
            outp[(size_t)((i*128 + b0 + row)*256 + t)*130 + v] = e0[r] + bo;
          }
        } else if (w == 8 && l15 < 2){
          const int v = 128 + l15;
          const float bo = boutp[i*130 + v];
          #pragma unroll
          for (int r = 0; r < 4; ++r){
            const int row = lg*4 + r;
            outp[(size_t)((i*128 + b0 + row)*256 + t)*130 + v] = e0[r] + bo;
          }
        }
        __syncthreads();
      }
    } // i
  } // tt
}

extern "C" void kernel_launch(void* const* d_in, const int* in_sizes, int n_in,
                              void* d_out, int out_size, void* d_ws, size_t ws_size,
                              hipStream_t stream){
  (void)in_sizes; (void)n_in; (void)out_size; (void)ws_size;
  const float* c     = (const float*)d_in[0];
  const int*   tgt   = (const int*)  d_in[1];
  const float* W_hid = (const float*)d_in[3];
  const float* b_hid = (const float*)d_in[4];
  const float* W1_ih = (const float*)d_in[5];
  const float* W1_hh = (const float*)d_in[6];
  const float* b1_ih = (const float*)d_in[7];
  const float* b1_hh = (const float*)d_in[8];
  const float* Wc_ih = (const float*)d_in[9];
  const float* Wc_hh = (const float*)d_in[10];
  const float* bc_ih = (const float*)d_in[11];
  const float* bc_hh = (const float*)d_in[12];
  const float* emb   = (const float*)d_in[13];
  const float* Wout  = (const float*)d_in[14];
  const float* bout  = (const float*)d_in[15];
  float* outp = (float*)d_out;

  short* ws = (short*)d_ws;
  short* W1hh_s  = ws;                 // 3 x 64nt x 8kt tiles
  short* W1ihA_s = ws + 786432;        // W1_ih[:, :256]
  short* W1ihB_s = ws + 1572864;       // W1_ih[:, 256:512]
  short* Wc_s    = ws + 2359296;       // [64nt][32kt]: ih k<768, hh k>=768
  short* Whid_s  = ws + 3407872;       // [256][256]
  short* Wout_s  = ws + 3473408;       // 3 x [144 pad][256]
  short* eprojb  = ws + 3584000;       // [3][130][256][4] bf16
  short* cpart   = ws + 3983360;       // [128 WG][3][16][4][256] bf16 C-frags
  float* cstate  = (float*)((char*)d_ws + 20549632);  // [128 WG][7][1024] f32x4

  for (int s = 0; s < 3; ++s){
    swz_kernel<<<1024,256,0,stream>>>(W1hh_s  + s*262144, W1_hh + s*262144, 256,   0, 1024,  8, 0,  8, 64);
    swz_kernel<<<1024,256,0,stream>>>(W1ihA_s + s*262144, W1_ih + s*524288, 512,   0, 1024,  8, 0,  8, 64);
    swz_kernel<<<1024,256,0,stream>>>(W1ihB_s + s*262144, W1_ih + s*524288, 512, 256, 1024,  8, 0,  8, 64);
    swz_kernel<<< 144,256,0,stream>>>(Wout_s  + s*36864,  Wout  + s*33280,  256,   0,  130,  8, 0,  8,  9);
  }
  swz_kernel<<<3072,256,0,stream>>>(Wc_s,   Wc_ih, 768, 0, 1024, 32,  0, 24, 64);
  swz_kernel<<<1024,256,0,stream>>>(Wc_s,   Wc_hh, 256, 0, 1024, 32, 24,  8, 64);
  swz_kernel<<< 256,256,0,stream>>>(Whid_s, W_hid, 256, 0,  512,  8,  0,  8, 16);
  eproj_kernel<<<3,1024,0,stream>>>(emb, b1_ih, b1_hh, W1ihA_s, eprojb);

  rnn_main<<<dim3(8,16),1024,0,stream>>>(c, tgt, b_hid, b1_ih, b1_hh, bc_ih, bc_hh,
                                         bout, eprojb, cpart, cstate,
                                         W1hh_s, W1ihA_s, W1ihB_s,
                                         Wc_s, Whid_s, Wout_s, outp);
}